// Round 7
// baseline (164.053 us; speedup 1.0000x reference)
//
#include <hip/hip_runtime.h>
#include <math.h>

#define BATCH 16
#define SEQ 64
#define NKEY 196
#define HIDDEN 1024
#define ATT_FEAT 2048
#define EMBED 512

using short8   = __attribute__((ext_vector_type(8))) short;
using f32x4    = __attribute__((ext_vector_type(4))) float;
using float4v  = __attribute__((ext_vector_type(4))) float;
using uint4v   = __attribute__((ext_vector_type(4))) unsigned;
using ushort4v = __attribute__((ext_vector_type(4))) unsigned short;

// exact truncation split: x = hi + lo + O(2^-16 |x|); bit-ops only
__device__ inline void split8(const float* f, short8& hi, short8& lo) {
    uint4v hp, lp;
    #pragma unroll
    for (int p = 0; p < 4; ++p) {
        unsigned u0 = __builtin_bit_cast(unsigned, f[2 * p + 0]);
        unsigned u1 = __builtin_bit_cast(unsigned, f[2 * p + 1]);
        unsigned m0 = u0 & 0xFFFF0000u;
        unsigned m1 = u1 & 0xFFFF0000u;
        hp[p] = m1 | (u0 >> 16);
        float l0 = f[2 * p + 0] - __builtin_bit_cast(float, m0);
        float l1 = f[2 * p + 1] - __builtin_bit_cast(float, m1);
        unsigned v0 = __builtin_bit_cast(unsigned, l0);
        unsigned v1 = __builtin_bit_cast(unsigned, l1);
        lp[p] = (v1 & 0xFFFF0000u) | (v0 >> 16);
    }
    hi = __builtin_bit_cast(short8, hp);
    lo = __builtin_bit_cast(short8, lp);
}

__device__ inline void split1(float x, unsigned short& h, unsigned short& l) {
    unsigned u = __builtin_bit_cast(unsigned, x);
    unsigned m = u & 0xFFFF0000u;
    h = (unsigned short)(u >> 16);
    float lo = x - __builtin_bit_cast(float, m);
    l = (unsigned short)(__builtin_bit_cast(unsigned, lo) >> 16);
}

// ---------------------------------------------------------------------------
// One-shot: W [K][N] f32  ->  Th/Tl [N][K] bf16 (truncation hi/lo split).
// ---------------------------------------------------------------------------
__global__ __launch_bounds__(256) void prep_split_transpose(
    const float* __restrict__ W, unsigned short* __restrict__ Th,
    unsigned short* __restrict__ Tl, int K, int N)
{
    __shared__ float tile[32][33];
    const int k0 = blockIdx.x * 32, n0 = blockIdx.y * 32;
    const int tid = threadIdx.x;

    {
        const int kl = tid >> 3;
        const int ng = (tid & 7) * 4;
        float4v v = *(const float4v*)(W + (size_t)(k0 + kl) * N + n0 + ng);
        tile[kl][ng + 0] = v.x; tile[kl][ng + 1] = v.y;
        tile[kl][ng + 2] = v.z; tile[kl][ng + 3] = v.w;
    }
    __syncthreads();
    {
        const int nl = tid >> 3;
        const int kg = (tid & 7) * 4;
        ushort4v h, l;
        #pragma unroll
        for (int j = 0; j < 4; ++j) {
            unsigned short hh, ll;
            split1(tile[kg + j][nl], hh, ll);
            h[j] = hh; l[j] = ll;
        }
        size_t off = (size_t)(n0 + nl) * K + k0 + kg;
        *(ushort4v*)(Th + off) = h;
        *(ushort4v*)(Tl + off) = l;
    }
}

// ---------------------------------------------------------------------------
// Barrier-free per-wave-K-split GEMM:
//   C[M,N] = A[M,K](f32) @ B[K,N] (+bias), B pre-split/transposed bf16 [N][K].
// Block = 64x64 output, BK=128, 4 waves; wave w owns k-slice [32w,32w+32):
// stages only its slice (A split in-register), reads only its slice,
// accumulates a full 64x64 k-partial (4x4 frags, reads/MFMA = 0.33).
// Disjoint LDS slices per wave -> NO barriers in the K-loop.
// End: 4-way cross-wave reduction via LDS (2 barriers total).
// Requires M%64==0, N%64==0, K%128==0, grid%8==0.
// ---------------------------------------------------------------------------
__global__ __launch_bounds__(256, 2) void gemm_mfma_ksplit(
    const float* __restrict__ A, const unsigned short* __restrict__ BTh,
    const unsigned short* __restrict__ BTl, const float* __restrict__ bias,
    float* __restrict__ C, int N, int K)
{
    __shared__ __align__(16) unsigned short lds[4 * 64 * 128];   // 64 KB
    char* base = (char*)lds;
    char* AhB = base;             // [64 rows][128 k] bf16, 16 KB
    char* AlB = base + 16384;
    char* BhB = base + 32768;     // [64 cols][128 k] bf16
    char* BlB = base + 49152;

    const int ncol = N >> 6;
    const int G  = gridDim.x;
    const int hh = blockIdx.x;
    const int t0 = (hh & 7) * (G >> 3) + (hh >> 3);   // XCD-contiguous tiles
    const int row0 = (t0 / ncol) << 6;
    const int col0 = (t0 % ncol) << 6;

    const int tid  = threadIdx.x;
    const int lane = tid & 63;
    const int w    = tid >> 6;        // wave = k-slice owner
    const int l15  = lane & 15;
    const int lg   = lane >> 4;

    const int kbW  = w << 6;              // wave k-slice byte base within a row
    const int xorS = (lane & 7) << 4;     // staging XOR (staging row = lane)
    const int rowB = lane << 8;           // lane * 256 B

    const float*          Ap  = A   + (size_t)(row0 + lane) * K + (w << 5);
    const unsigned short* Bhp = BTh + (size_t)(col0 + lane) * K + (w << 5);
    const unsigned short* Blp = BTl + (size_t)(col0 + lane) * K + (w << 5);

    f32x4 acc[4][4] = {};

    float4v Ar[8];
    short8  Bhr[4], Blr[4];

    auto load_regs = [&](int kf) {        // kf in elements (f32 == bf16 count)
        #pragma unroll
        for (int q = 0; q < 8; ++q)
            Ar[q] = *(const float4v*)(Ap + kf + q * 4);
        #pragma unroll
        for (int q = 0; q < 4; ++q) {
            Bhr[q] = *(const short8*)(Bhp + kf + q * 8);
            Blr[q] = *(const short8*)(Blp + kf + q * 8);
        }
    };

    auto stage = [&]() {
        float f[32];
        #pragma unroll
        for (int q = 0; q < 8; ++q) {
            f[q*4+0] = Ar[q].x; f[q*4+1] = Ar[q].y;
            f[q*4+2] = Ar[q].z; f[q*4+3] = Ar[q].w;
        }
        #pragma unroll
        for (int h = 0; h < 4; ++h) {
            short8 hi, lo;
            split8(f + h * 8, hi, lo);
            const int off = rowB + ((kbW + h * 16) ^ xorS);
            *(short8*)(AhB + off) = hi;
            *(short8*)(AlB + off) = lo;
            *(short8*)(BhB + off) = Bhr[h];
            *(short8*)(BlB + off) = Blr[h];
        }
    };

    auto compute = [&]() {
        short8 ah[4], al[4], bh[4], bl[4];
        const int fr = kbW + (lg << 4);
        #pragma unroll
        for (int m = 0; m < 4; ++m) {
            const int r   = m * 16 + l15;
            const int off = (r << 8) + (fr ^ ((r & 7) << 4));
            ah[m] = *(const short8*)(AhB + off);
            al[m] = *(const short8*)(AlB + off);
            bh[m] = *(const short8*)(BhB + off);
            bl[m] = *(const short8*)(BlB + off);
        }
        __builtin_amdgcn_s_setprio(1);
        #pragma unroll
        for (int m = 0; m < 4; ++m)
            #pragma unroll
            for (int n = 0; n < 4; ++n) {
                acc[m][n] = __builtin_amdgcn_mfma_f32_16x16x32_bf16(ah[m], bh[n], acc[m][n], 0, 0, 0);
                acc[m][n] = __builtin_amdgcn_mfma_f32_16x16x32_bf16(ah[m], bl[n], acc[m][n], 0, 0, 0);
                acc[m][n] = __builtin_amdgcn_mfma_f32_16x16x32_bf16(al[m], bh[n], acc[m][n], 0, 0, 0);
            }
        __builtin_amdgcn_s_setprio(0);
    };

    const int nt = K >> 7;                // BK = 128
    load_regs(0);
    for (int t = 0; t < nt; ++t) {
        stage();                          // wave-private LDS slice; no barrier
        if (t + 1 < nt) load_regs((t + 1) << 7);   // prefetch next tile
        compute();
    }

    // ---- cross-wave k-partial reduction via LDS ----
    __syncthreads();
    float* red = (float*)(base + (w << 14));       // w * 16 KB, [64][64] f32
    #pragma unroll
    for (int m = 0; m < 4; ++m)
        #pragma unroll
        for (int n = 0; n < 4; ++n)
            #pragma unroll
            for (int v = 0; v < 4; ++v) {
                const int r = m * 16 + lg * 4 + v;
                const int c = n * 16 + l15;
                red[(r << 6) + c] = acc[m][n][v];
            }
    __syncthreads();
    const float* r0p = (const float*)base;
    #pragma unroll
    for (int j = 0; j < 4; ++j) {
        const int i = (j << 10) + (tid << 2);      // 4096 outs, 4/thread/iter
        const int r = i >> 6, c = i & 63;
        f32x4 s = *(const f32x4*)(r0p + i)
                + *(const f32x4*)(r0p + 4096 + i)
                + *(const f32x4*)(r0p + 8192 + i)
                + *(const f32x4*)(r0p + 12288 + i);
        if (bias) {
            float4v bv = *(const float4v*)(bias + col0 + c);
            s += bv;
        }
        *(float4v*)(C + (size_t)(row0 + r) * N + col0 + c) = s;
    }
}

// ---------------------------------------------------------------------------
// scores[b,s,n] = 2 * sum_e w[e] * sigmoid(2*(Wh+Uv))  (Sum(w) shift dropped)
// ---------------------------------------------------------------------------
__global__ __launch_bounds__(256) void scores_kernel(
    const float* __restrict__ Wh, const float* __restrict__ Uv,
    const float* __restrict__ wvec, const int* __restrict__ mask,
    float* __restrict__ scores)
{
    const int n0 = blockIdx.x * 16;
    const int s0 = blockIdx.y * 16;
    const int b  = blockIdx.z;
    const int tid = threadIdx.x;
    const int tx = tid & 15;
    const int ty = tid >> 4;

    __shared__ float whs[16][64];
    __shared__ float uvs[16][64];

    const float KC = -2.8853900817779268f;   // -2*log2(e)

    const int r  = tid >> 4;
    const int c4 = tid & 15;
    const int sr = s0 + r;
    const int nr_raw = n0 + r;
    const int nr = nr_raw < NKEY ? nr_raw : NKEY - 1;

    const float* WhRow = Wh + (size_t)(b * SEQ + sr) * EMBED;
    const float* UvRow = Uv + (size_t)(b * NKEY + nr) * EMBED;

    float acc0 = 0.f, acc1 = 0.f, acc2 = 0.f, acc3 = 0.f;

    for (int e0 = 0; e0 < EMBED; e0 += 64) {
        float4v wv = *(const float4v*)(WhRow + e0 + c4 * 4);
        float4v uv = *(const float4v*)(UvRow + e0 + c4 * 4);
        *(float4v*)&whs[r][(c4 ^ r) << 2] = wv;
        *(float4v*)&uvs[r][(c4 ^ r) << 2] = uv;
        __syncthreads();

        #pragma unroll
        for (int c = 0; c < 16; ++c) {
            float4v whv = *(const float4v*)&whs[ty][(c ^ ty) << 2];
            float4v uvv = *(const float4v*)&uvs[tx][(c ^ tx) << 2];
            const float w0 = wvec[e0 + c * 4 + 0];
            const float w1 = wvec[e0 + c * 4 + 1];
            const float w2 = wvec[e0 + c * 4 + 2];
            const float w3 = wvec[e0 + c * 4 + 3];
            float t0 = __builtin_amdgcn_exp2f(KC * (whv.x + uvv.x));
            float t1 = __builtin_amdgcn_exp2f(KC * (whv.y + uvv.y));
            float t2 = __builtin_amdgcn_exp2f(KC * (whv.z + uvv.z));
            float t3 = __builtin_amdgcn_exp2f(KC * (whv.w + uvv.w));
            acc0 = fmaf(w0, __builtin_amdgcn_rcpf(1.f + t0), acc0);
            acc1 = fmaf(w1, __builtin_amdgcn_rcpf(1.f + t1), acc1);
            acc2 = fmaf(w2, __builtin_amdgcn_rcpf(1.f + t2), acc2);
            acc3 = fmaf(w3, __builtin_amdgcn_rcpf(1.f + t3), acc3);
        }
        __syncthreads();
    }

    float sc = 2.f * ((acc0 + acc1) + (acc2 + acc3));
    const int n = n0 + tx;
    if (n < NKEY) {
        float v = (mask[b * NKEY + n] == 0) ? -1e9f : sc;
        scores[(size_t)(b * SEQ + s0 + ty) * NKEY + n] = v;
    }
}

// ---------------------------------------------------------------------------
// In-place row softmax over N=196. One wave per row.
// ---------------------------------------------------------------------------
__global__ __launch_bounds__(64) void softmax_kernel(float* __restrict__ sw)
{
    const int row = blockIdx.x;
    const int lane = threadIdx.x;
    float v[4];
    float mx = -INFINITY;
    #pragma unroll
    for (int k = 0; k < 4; ++k) {
        int n = lane + 64 * k;
        v[k] = (n < NKEY) ? sw[(size_t)row * NKEY + n] : -INFINITY;
        mx = fmaxf(mx, v[k]);
    }
    #pragma unroll
    for (int off = 32; off; off >>= 1) mx = fmaxf(mx, __shfl_xor(mx, off));
    float sum = 0.f;
    #pragma unroll
    for (int k = 0; k < 4; ++k) {
        v[k] = __expf(v[k] - mx);
        if (lane + 64 * k < NKEY) sum += v[k];
    }
    #pragma unroll
    for (int off = 32; off; off >>= 1) sum += __shfl_xor(sum, off);
    const float inv = __fdividef(1.f, sum);
    #pragma unroll
    for (int k = 0; k < 4; ++k) {
        int n = lane + 64 * k;
        if (n < NKEY) sw[(size_t)row * NKEY + n] = v[k] * inv;
    }
}

// ---------------------------------------------------------------------------
// attn[b,s,f] = sum_n weights[b,s,n] * feats[b,n,f]
// 256 threads x float4 = 1024 f-cols, 8 s-rows; weights transposed in LDS.
// ---------------------------------------------------------------------------
__global__ __launch_bounds__(256) void attn_kernel(
    const float* __restrict__ weights, const float* __restrict__ feats,
    float* __restrict__ out)
{
    const int t   = threadIdx.x;
    const int col = blockIdx.x * 1024 + t * 4;
    const int s0  = blockIdx.y * 8;
    const int b   = blockIdx.z;

    __shared__ float wt[NKEY][8];
    for (int i = t; i < 8 * NKEY; i += 256) {
        int s = i / NKEY, n = i % NKEY;
        wt[n][s] = weights[(size_t)(b * SEQ + s0 + s) * NKEY + n];
    }
    __syncthreads();

    const float* fp = feats + (size_t)b * NKEY * ATT_FEAT + col;

    float4v acc[8] = {};
    #pragma unroll 4
    for (int n = 0; n < NKEY; ++n) {
        float4v f  = *(const float4v*)(fp + (size_t)n * ATT_FEAT);
        float4v w0 = *(const float4v*)&wt[n][0];
        float4v w1 = *(const float4v*)&wt[n][4];
        acc[0] += w0.x * f;
        acc[1] += w0.y * f;
        acc[2] += w0.z * f;
        acc[3] += w0.w * f;
        acc[4] += w1.x * f;
        acc[5] += w1.y * f;
        acc[6] += w1.z * f;
        acc[7] += w1.w * f;
    }

    float* op = out + (size_t)(b * SEQ + s0) * ATT_FEAT + col;
    #pragma unroll
    for (int s = 0; s < 8; ++s)
        *(float4v*)(op + (size_t)s * ATT_FEAT) = acc[s];
}

// ---------------------------------------------------------------------------
extern "C" void kernel_launch(void* const* d_in, const int* in_sizes, int n_in,
                              void* d_out, int out_size, void* d_ws, size_t ws_size,
                              hipStream_t stream)
{
    const float* hidden = (const float*)d_in[0];
    const float* feats  = (const float*)d_in[1];
    const int*   mask   = (const int*)  d_in[2];
    const float* w_h    = (const float*)d_in[3];
    const float* w_u    = (const float*)d_in[4];
    const float* bvec   = (const float*)d_in[5];
    const float* wvec   = (const float*)d_in[6];

    float* out         = (float*)d_out;
    float* attn_out    = out;
    float* weights_out = out + (size_t)BATCH * SEQ * ATT_FEAT;

    // workspace layout (~20.4 MB)
    float* Wh = (float*)d_ws;                                   // 1024x512 f32
    float* Uv = Wh + (size_t)BATCH * SEQ * EMBED;               // 3136x512 f32
    unsigned short* WhTh = (unsigned short*)(Uv + (size_t)BATCH * NKEY * EMBED);
    unsigned short* WhTl = WhTh + (size_t)EMBED * HIDDEN;       // [512][1024] bf16
    unsigned short* WuTh = WhTl + (size_t)EMBED * HIDDEN;
    unsigned short* WuTl = WuTh + (size_t)EMBED * ATT_FEAT;     // [512][2048] bf16

    // P1/P2: pre-split + transpose weights (one-shot, memory-bound)
    prep_split_transpose<<<dim3(HIDDEN / 32, EMBED / 32), 256, 0, stream>>>(
        w_h, WhTh, WhTl, HIDDEN, EMBED);
    prep_split_transpose<<<dim3(ATT_FEAT / 32, EMBED / 32), 256, 0, stream>>>(
        w_u, WuTh, WuTl, ATT_FEAT, EMBED);

    // K1: Wh = hidden @ w_h          grid 128 = 8*16
    gemm_mfma_ksplit<<<dim3((BATCH * SEQ / 64) * (EMBED / 64)), 256, 0, stream>>>(
        hidden, WhTh, WhTl, nullptr, Wh, EMBED, HIDDEN);

    // K2: Uv = feats @ w_u + b       grid 392 = 8*49
    gemm_mfma_ksplit<<<dim3((BATCH * NKEY / 64) * (EMBED / 64)), 256, 0, stream>>>(
        feats, WuTh, WuTl, bvec, Uv, EMBED, ATT_FEAT);

    // K3: scores (+mask) -> weights region of d_out
    scores_kernel<<<dim3((NKEY + 15) / 16, SEQ / 16, BATCH), 256, 0, stream>>>(
        Wh, Uv, wvec, mask, weights_out);

    // K4: softmax in place
    softmax_kernel<<<dim3(BATCH * SEQ), 64, 0, stream>>>(weights_out);

    // K5: attn_feats = weights @ feats
    attn_kernel<<<dim3(ATT_FEAT / 1024, SEQ / 8, BATCH), 256, 0, stream>>>(
        weights_out, feats, attn_out);
}